// Round 1
// baseline (347.821 us; speedup 1.0000x reference)
//
#include <hip/hip_runtime.h>

typedef unsigned short u16;
typedef unsigned int u32;
typedef __attribute__((ext_vector_type(8))) short bf16x8;
typedef __attribute__((ext_vector_type(4))) float f32x4;

#define NROWS 400000
#define DIM 192
#define ROWS_PER_BLK 64
#define NBLK (NROWS / ROWS_PER_BLK) /* 6250 */
#define FROWS 128
#define FBLK (NROWS / FROWS) /* 3125 */
#define BN_EPS 1e-5f

__device__ __forceinline__ u16 f2b(float f) {
  union { float f; u32 u; } v; v.f = f;
  return (u16)((v.u + 0x7fffu + ((v.u >> 16) & 1u)) >> 16);
}
__device__ __forceinline__ float b2f(u16 h) {
  union { u32 u; float f; } v; v.u = ((u32)h) << 16;
  return v.f;
}

// Transpose weights to bf16 col-major: Wt[h*192 + d] = W[d*192 + h]
__global__ void prep_w(const float* __restrict__ W1, const float* __restrict__ W2,
                       u16* __restrict__ W1t, u16* __restrict__ W2t) {
  int idx = blockIdx.x * 256 + threadIdx.x;
  if (idx < DIM * DIM) {
    int h = idx / DIM, d = idx % DIM;
    W1t[idx] = f2b(W1[d * DIM + h]);
    W2t[idx] = f2b(W2[d * DIM + h]);
  }
}

// Fused GEMM (+ bias) + per-block column stats partials.
// LAYER==1: A = Xf (fp32), out -> Ybuf.
// LAYER==2: A = BN1+ReLU(Ybuf) (bf16, fused in staging), out -> Ybuf IN PLACE (same rows).
template <int LAYER>
__global__ __launch_bounds__(256) void gemm_bn(
    const float* __restrict__ Xf, u16* Ybuf, const u16* __restrict__ Wt,
    const float* __restrict__ bias, const float* __restrict__ scale_in,
    const float* __restrict__ shift_in, float* __restrict__ partials) {
  __shared__ u16 As[64][200];  // pad 192->200 (400B row): 2-way-free LDS banks
  const int t = threadIdx.x;
  const int bid = blockIdx.x;
  const size_t row0 = (size_t)bid * ROWS_PER_BLK;

  if (LAYER == 1) {
    const float4* Xv = (const float4*)(Xf + row0 * DIM);
#pragma unroll
    for (int j = 0; j < 12; ++j) {
      int e = j * 256 + t;  // 64 rows x 48 float4
      int r = e / 48, c4 = e % 48;
      float4 v = Xv[e];
      ushort4 o;
      o.x = f2b(v.x); o.y = f2b(v.y); o.z = f2b(v.z); o.w = f2b(v.w);
      *(ushort4*)&As[r][c4 * 4] = o;
    }
  } else {
    const u16* Yin = Ybuf + row0 * DIM;
#pragma unroll
    for (int j = 0; j < 6; ++j) {
      int e = j * 256 + t;  // 64 rows x 24 vec8
      int r = e / 24, c8 = e % 24;
      int cb = c8 * 8;
      uint4 p = *(const uint4*)(Yin + (size_t)r * DIM + cb);
      u32 pw[4] = {p.x, p.y, p.z, p.w};
      u16 o[8];
#pragma unroll
      for (int i = 0; i < 4; ++i) {
        float lo = b2f((u16)(pw[i] & 0xffffu));
        float hi = b2f((u16)(pw[i] >> 16));
        o[2 * i]     = f2b(fmaxf(lo * scale_in[cb + 2 * i] + shift_in[cb + 2 * i], 0.f));
        o[2 * i + 1] = f2b(fmaxf(hi * scale_in[cb + 2 * i + 1] + shift_in[cb + 2 * i + 1], 0.f));
      }
      ushort4 o0 = {o[0], o[1], o[2], o[3]};
      ushort4 o1 = {o[4], o[5], o[6], o[7]};
      *(ushort4*)&As[r][cb] = o0;
      *(ushort4*)&As[r][cb + 4] = o1;
    }
  }
  __syncthreads();

  const int lane = t & 63, wv = t >> 6;
  const int cb = wv * 48;            // wave owns 48 output cols
  const int lrow = lane & 15;        // A row / B col within 16-tile
  const int kgrp = (lane >> 4) * 8;  // k offset within 32-step

  f32x4 acc[4][3];
#pragma unroll
  for (int rt = 0; rt < 4; ++rt)
#pragma unroll
    for (int ct = 0; ct < 3; ++ct) acc[rt][ct] = (f32x4){0.f, 0.f, 0.f, 0.f};

#pragma unroll
  for (int ks = 0; ks < 6; ++ks) {
    int k0 = ks * 32 + kgrp;
    bf16x8 a[4], b[3];
#pragma unroll
    for (int rt = 0; rt < 4; ++rt) a[rt] = *(const bf16x8*)&As[rt * 16 + lrow][k0];
#pragma unroll
    for (int ct = 0; ct < 3; ++ct)
      b[ct] = *(const bf16x8*)(Wt + (size_t)(cb + ct * 16 + lrow) * DIM + k0);
#pragma unroll
    for (int rt = 0; rt < 4; ++rt)
#pragma unroll
      for (int ct = 0; ct < 3; ++ct)
        acc[rt][ct] = __builtin_amdgcn_mfma_f32_16x16x32_bf16(a[rt], b[ct], acc[rt][ct], 0, 0, 0);
  }

  // Epilogue: bias add, store bf16, per-column (sum, sumsq) partials
  const int orow = (lane >> 4) * 4;
  float bload[3], s[3] = {0.f, 0.f, 0.f}, q[3] = {0.f, 0.f, 0.f};
#pragma unroll
  for (int ct = 0; ct < 3; ++ct) bload[ct] = bias[cb + ct * 16 + lrow];
  u16* Yo = Ybuf + row0 * DIM;
#pragma unroll
  for (int rt = 0; rt < 4; ++rt)
#pragma unroll
    for (int ct = 0; ct < 3; ++ct) {
      f32x4 v = acc[rt][ct];
#pragma unroll
      for (int i = 0; i < 4; ++i) {
        float f = v[i] + bload[ct];
        s[ct] += f;
        q[ct] += f * f;
        Yo[(size_t)(rt * 16 + orow + i) * DIM + cb + ct * 16 + lrow] = f2b(f);
      }
    }
#pragma unroll
  for (int ct = 0; ct < 3; ++ct) {
    s[ct] += __shfl_xor(s[ct], 16); s[ct] += __shfl_xor(s[ct], 32);
    q[ct] += __shfl_xor(q[ct], 16); q[ct] += __shfl_xor(q[ct], 32);
  }
  if (lane < 16) {
#pragma unroll
    for (int ct = 0; ct < 3; ++ct) {
      partials[(size_t)bid * 384 + cb + ct * 16 + lane] = s[ct];
      partials[(size_t)bid * 384 + 192 + cb + ct * 16 + lane] = q[ct];
    }
  }
}

// Reduce partials -> BN affine params (scale = g/sqrt(var+eps), shift = be - mean*scale)
__global__ __launch_bounds__(256) void bn_finalize(
    const float* __restrict__ partials, int nblk, const float* __restrict__ g,
    const float* __restrict__ be, float* __restrict__ scale,
    float* __restrict__ shift, float* accum) {
  int c = blockIdx.x;  // 192 blocks, one per column
  int t = threadIdx.x;
  float s = 0.f, q = 0.f;
  for (int i = t; i < nblk; i += 256) {
    s += partials[(size_t)i * 384 + c];
    q += partials[(size_t)i * 384 + 192 + c];
  }
#pragma unroll
  for (int off = 1; off < 64; off <<= 1) {
    s += __shfl_xor(s, off);
    q += __shfl_xor(q, off);
  }
  __shared__ float ss[4], qq[4];
  int lane = t & 63, wv = t >> 6;
  if (lane == 0) { ss[wv] = s; qq[wv] = q; }
  __syncthreads();
  if (t == 0) {
    s = ss[0] + ss[1] + ss[2] + ss[3];
    q = qq[0] + qq[1] + qq[2] + qq[3];
    float mean = s / (float)NROWS;
    float var = q / (float)NROWS - mean * mean;
    float inv = rsqrtf(var + BN_EPS);
    float sc = g[c] * inv;
    scale[c] = sc;
    shift[c] = be[c] - mean * sc;
    if (c == 0) *accum = 0.f;
  }
}

// BN2+ReLU + Linear[192x8] + sigmoid + log_softmax + NLL, accumulated.
__global__ __launch_bounds__(256) void final_loss(
    const u16* __restrict__ Y2, const int* __restrict__ labels,
    const float* __restrict__ scale2, const float* __restrict__ shift2,
    const float* __restrict__ W3, const float* __restrict__ b3, float* accum) {
  __shared__ u16 Hs[128][204];  // pad: 2-way-free banks for ushort4 reads
  __shared__ float W3s[DIM * 8];
  __shared__ float b3s[8];
  __shared__ float red[4];
  const int t = threadIdx.x;
  const size_t row0 = (size_t)blockIdx.x * FROWS;

  for (int j = t; j < DIM * 8; j += 256) W3s[j] = W3[j];
  if (t < 8) b3s[t] = b3[t];
#pragma unroll
  for (int j = 0; j < 12; ++j) {
    int e = j * 256 + t;  // 128 rows x 24 vec8
    int r = e / 24, c8 = e % 24;
    int cb = c8 * 8;
    uint4 p = *(const uint4*)(Y2 + (row0 + r) * DIM + cb);
    u32 pw[4] = {p.x, p.y, p.z, p.w};
    u16 o[8];
#pragma unroll
    for (int i = 0; i < 4; ++i) {
      float lo = b2f((u16)(pw[i] & 0xffffu));
      float hi = b2f((u16)(pw[i] >> 16));
      o[2 * i]     = f2b(fmaxf(lo * scale2[cb + 2 * i] + shift2[cb + 2 * i], 0.f));
      o[2 * i + 1] = f2b(fmaxf(hi * scale2[cb + 2 * i + 1] + shift2[cb + 2 * i + 1], 0.f));
    }
    ushort4 o0 = {o[0], o[1], o[2], o[3]};
    ushort4 o1 = {o[4], o[5], o[6], o[7]};
    *(ushort4*)&Hs[r][cb] = o0;
    *(ushort4*)&Hs[r][cb + 4] = o1;
  }
  __syncthreads();

  const int r = t >> 1, cq = t & 1;  // 2 threads/row: classes cq*4..cq*4+3
  float a0 = 0.f, a1 = 0.f, a2 = 0.f, a3 = 0.f;
#pragma unroll
  for (int k4 = 0; k4 < 48; ++k4) {
    ushort4 h4 = *(const ushort4*)&Hs[r][k4 * 4];
    u16 hv[4] = {h4.x, h4.y, h4.z, h4.w};
#pragma unroll
    for (int i = 0; i < 4; ++i) {
      float hf = b2f(hv[i]);
      const float* w = &W3s[(k4 * 4 + i) * 8 + cq * 4];
      a0 += hf * w[0]; a1 += hf * w[1]; a2 += hf * w[2]; a3 += hf * w[3];
    }
  }
  float p0 = 1.f / (1.f + expf(-(a0 + b3s[cq * 4 + 0])));
  float p1 = 1.f / (1.f + expf(-(a1 + b3s[cq * 4 + 1])));
  float p2 = 1.f / (1.f + expf(-(a2 + b3s[cq * 4 + 2])));
  float p3 = 1.f / (1.f + expf(-(a3 + b3s[cq * 4 + 3])));
  float m4 = fmaxf(fmaxf(p0, p1), fmaxf(p2, p3));
  float m = fmaxf(m4, __shfl_xor(m4, 1));
  float e = expf(p0 - m) + expf(p1 - m) + expf(p2 - m) + expf(p3 - m);
  float sum = e + __shfl_xor(e, 1);
  float lg = logf(sum);
  int lab = labels[row0 + r];
  float contrib = 0.f;
  if ((lab >> 2) == cq) {
    int li = lab & 3;
    float pl = li == 0 ? p0 : li == 1 ? p1 : li == 2 ? p2 : p3;
    contrib = m + lg - pl;  // = -log_softmax[label]
  }
#pragma unroll
  for (int off = 1; off < 64; off <<= 1) contrib += __shfl_xor(contrib, off);
  if ((t & 63) == 0) red[t >> 6] = contrib;
  __syncthreads();
  if (t == 0) atomicAdd(accum, red[0] + red[1] + red[2] + red[3]);
}

__global__ void finalize(const float* __restrict__ accum, float* __restrict__ out) {
  if (threadIdx.x == 0) out[0] = accum[0] / (float)NROWS;
}

extern "C" void kernel_launch(void* const* d_in, const int* in_sizes, int n_in,
                              void* d_out, int out_size, void* d_ws, size_t ws_size,
                              hipStream_t stream) {
  const float* inputs = (const float*)d_in[0];
  const int* labels   = (const int*)d_in[1];
  const float* W1  = (const float*)d_in[2];
  const float* b1  = (const float*)d_in[3];
  const float* g1  = (const float*)d_in[4];
  const float* be1 = (const float*)d_in[5];
  const float* W2  = (const float*)d_in[6];
  const float* b2  = (const float*)d_in[7];
  const float* g2  = (const float*)d_in[8];
  const float* be2 = (const float*)d_in[9];
  const float* W3  = (const float*)d_in[10];
  const float* b3  = (const float*)d_in[11];
  float* out = (float*)d_out;

  char* ws = (char*)d_ws;
  u16* W1t      = (u16*)(ws + 0);
  u16* W2t      = (u16*)(ws + 73728);
  float* scale1 = (float*)(ws + 147456);
  float* shift1 = (float*)(ws + 148224);
  float* scale2 = (float*)(ws + 148992);
  float* shift2 = (float*)(ws + 149760);
  float* accum  = (float*)(ws + 150528);
  float* partials = (float*)(ws + 151040);            // 6250*384*4 = 9.6 MB
  u16* Ybuf     = (u16*)(ws + 16000000);              // 400000*192*2 = 153.6 MB

  prep_w<<<144, 256, 0, stream>>>(W1, W2, W1t, W2t);
  gemm_bn<1><<<NBLK, 256, 0, stream>>>(inputs, Ybuf, W1t, b1, nullptr, nullptr, partials);
  bn_finalize<<<DIM, 256, 0, stream>>>(partials, NBLK, g1, be1, scale1, shift1, accum);
  gemm_bn<2><<<NBLK, 256, 0, stream>>>(nullptr, Ybuf, W2t, b2, scale1, shift1, partials);
  bn_finalize<<<DIM, 256, 0, stream>>>(partials, NBLK, g2, be2, scale2, shift2, accum);
  final_loss<<<FBLK, 256, 0, stream>>>(Ybuf, labels, scale2, shift2, W3, b3, accum);
  finalize<<<1, 64, 0, stream>>>(accum, out);
}

// Round 2
// 321.860 us; speedup vs baseline: 1.0807x; 1.0807x over previous
//
#include <hip/hip_runtime.h>

typedef unsigned short u16;
typedef unsigned int u32;
typedef __attribute__((ext_vector_type(8))) short bf16x8;
typedef __attribute__((ext_vector_type(4))) short bf16x4;
typedef __attribute__((ext_vector_type(4))) float f32x4;

#define NROWS 400000
#define DIM 192
#define RPB 128
#define NBLK (NROWS / RPB) /* 3125 */
#define SLAB 25
#define RBLK (NBLK / SLAB) /* 125 */
#define LDW 208 /* GEMM LDS pitch in u16: 416B, 16B-aligned rows */
#define BN_EPS 1e-5f

__device__ __forceinline__ u16 f2b(float f) {
  union { float f; u32 u; } v; v.f = f;
  return (u16)((v.u + 0x7fffu + ((v.u >> 16) & 1u)) >> 16);
}
__device__ __forceinline__ float b2f(u16 h) {
  union { u32 u; float f; } v; v.u = ((u32)h) << 16;
  return v.f;
}

// Weights -> bf16, transposed col-major. W3 padded to 16 cols (8 zeros).
__global__ void prep_w(const float* __restrict__ W1, const float* __restrict__ W2,
                       const float* __restrict__ W3, u16* __restrict__ W1t,
                       u16* __restrict__ W2t, u16* __restrict__ W3t) {
  int idx = blockIdx.x * 256 + threadIdx.x;
  if (idx < DIM * DIM) {
    int h = idx / DIM, d = idx % DIM;
    W1t[idx] = f2b(W1[d * DIM + h]);
    W2t[idx] = f2b(W2[d * DIM + h]);
  } else if (idx < DIM * DIM + 16 * DIM) {
    int j = idx - DIM * DIM;
    int c = j / DIM, k = j % DIM;
    W3t[j] = (c < 8) ? f2b(W3[k * 8 + c]) : (u16)0;
  }
}

// Fused GEMM (+bias) + per-block column (sum,sumsq) partials.
// Swapped-operand MFMA: lane holds 4 CONSECUTIVE COLS of one row -> ushort4 stores.
// LAYER==1: A = X (fp32->bf16). LAYER==2: A = ReLU(BN1(Ybuf)), in-place output.
template <int LAYER>
__global__ __launch_bounds__(256) void gemm_bn(
    const float* __restrict__ Xf, u16* Ybuf, const u16* __restrict__ Wt,
    const float* __restrict__ bias, const float* __restrict__ scale_in,
    const float* __restrict__ shift_in, float* __restrict__ partials) {
  __shared__ u16 As[RPB][LDW];
  const int t = threadIdx.x;
  const int bid = blockIdx.x;
  const size_t row0 = (size_t)bid * RPB;

  if (LAYER == 1) {
    const float4* Xv = (const float4*)(Xf + row0 * DIM);
#pragma unroll
    for (int j = 0; j < 24; ++j) {
      int e = j * 256 + t;  // 128 rows x 48 float4
      int r = e / 48, c4 = e % 48;
      float4 v = Xv[e];
      ushort4 o;
      o.x = f2b(v.x); o.y = f2b(v.y); o.z = f2b(v.z); o.w = f2b(v.w);
      *(ushort4*)&As[r][c4 * 4] = o;
    }
  } else {
    const u16* Yin = Ybuf + row0 * DIM;
#pragma unroll
    for (int j = 0; j < 12; ++j) {
      int e = j * 256 + t;  // 128 rows x 24 vec8
      int r = e / 24, cb8 = (e % 24) * 8;
      uint4 p = *(const uint4*)(Yin + (size_t)r * DIM + cb8);
      float4 sc0 = *(const float4*)&scale_in[cb8];
      float4 sc1 = *(const float4*)&scale_in[cb8 + 4];
      float4 sh0 = *(const float4*)&shift_in[cb8];
      float4 sh1 = *(const float4*)&shift_in[cb8 + 4];
      u32 pw[4] = {p.x, p.y, p.z, p.w};
      float scv[8] = {sc0.x, sc0.y, sc0.z, sc0.w, sc1.x, sc1.y, sc1.z, sc1.w};
      float shv[8] = {sh0.x, sh0.y, sh0.z, sh0.w, sh1.x, sh1.y, sh1.z, sh1.w};
      u16 o[8];
#pragma unroll
      for (int i = 0; i < 4; ++i) {
        float lo = b2f((u16)(pw[i] & 0xffffu));
        float hi = b2f((u16)(pw[i] >> 16));
        o[2 * i]     = f2b(fmaxf(lo * scv[2 * i] + shv[2 * i], 0.f));
        o[2 * i + 1] = f2b(fmaxf(hi * scv[2 * i + 1] + shv[2 * i + 1], 0.f));
      }
      ushort4 o0 = {o[0], o[1], o[2], o[3]};
      ushort4 o1 = {o[4], o[5], o[6], o[7]};
      *(ushort4*)&As[r][cb8] = o0;
      *(ushort4*)&As[r][cb8 + 4] = o1;
    }
  }
  __syncthreads();

  const int lane = t & 63, wv = t >> 6;
  const int cb = wv * 48;       // wave owns 48 output cols
  const int lr = lane & 15;
  const int g = lane >> 4;      // 0..3
  const int kg = g * 8;

  f32x4 acc[8][3];
#pragma unroll
  for (int rt = 0; rt < 8; ++rt)
#pragma unroll
    for (int ct = 0; ct < 3; ++ct) acc[rt][ct] = (f32x4){0.f, 0.f, 0.f, 0.f};

#pragma unroll
  for (int ks = 0; ks < 6; ++ks) {
    const int k0 = ks * 32 + kg;
    bf16x8 b0 = *(const bf16x8*)(Wt + (size_t)(cb + lr) * DIM + k0);
    bf16x8 b1 = *(const bf16x8*)(Wt + (size_t)(cb + 16 + lr) * DIM + k0);
    bf16x8 b2 = *(const bf16x8*)(Wt + (size_t)(cb + 32 + lr) * DIM + k0);
#pragma unroll
    for (int rt = 0; rt < 8; ++rt) {
      bf16x8 a = *(const bf16x8*)&As[rt * 16 + lr][k0];
      acc[rt][0] = __builtin_amdgcn_mfma_f32_16x16x32_bf16(b0, a, acc[rt][0], 0, 0, 0);
      acc[rt][1] = __builtin_amdgcn_mfma_f32_16x16x32_bf16(b1, a, acc[rt][1], 0, 0, 0);
      acc[rt][2] = __builtin_amdgcn_mfma_f32_16x16x32_bf16(b2, a, acc[rt][2], 0, 0, 0);
    }
  }

  // Epilogue: lane holds row rt*16+lr, cols cb+ct*16+g*4+{0..3}
  float4 bl[3];
#pragma unroll
  for (int ct = 0; ct < 3; ++ct) bl[ct] = *(const float4*)&bias[cb + ct * 16 + g * 4];
  f32x4 s[3], q[3];
#pragma unroll
  for (int ct = 0; ct < 3; ++ct) { s[ct] = (f32x4){0,0,0,0}; q[ct] = (f32x4){0,0,0,0}; }
  u16* Yo = Ybuf + row0 * DIM;
#pragma unroll
  for (int rt = 0; rt < 8; ++rt) {
    const int row = rt * 16 + lr;
#pragma unroll
    for (int ct = 0; ct < 3; ++ct) {
      f32x4 v = acc[rt][ct];
      float f0 = v[0] + bl[ct].x, f1 = v[1] + bl[ct].y;
      float f2 = v[2] + bl[ct].z, f3 = v[3] + bl[ct].w;
      ushort4 o = {f2b(f0), f2b(f1), f2b(f2), f2b(f3)};
      *(ushort4*)(Yo + (size_t)row * DIM + cb + ct * 16 + g * 4) = o;
      s[ct][0] += f0; s[ct][1] += f1; s[ct][2] += f2; s[ct][3] += f3;
      q[ct][0] += f0 * f0; q[ct][1] += f1 * f1; q[ct][2] += f2 * f2; q[ct][3] += f3 * f3;
    }
  }
  // reduce over rows (lane&15 dimension)
#pragma unroll
  for (int ct = 0; ct < 3; ++ct)
#pragma unroll
    for (int off = 1; off <= 8; off <<= 1)
#pragma unroll
      for (int i = 0; i < 4; ++i) {
        s[ct][i] += __shfl_xor(s[ct][i], off);
        q[ct][i] += __shfl_xor(q[ct][i], off);
      }
  if (lr == 0) {
    size_t base = (size_t)bid * 384 + cb + g * 4;
#pragma unroll
    for (int ct = 0; ct < 3; ++ct) {
      *(f32x4*)&partials[base + ct * 16] = s[ct];
      *(f32x4*)&partials[base + ct * 16 + 192] = q[ct];
    }
  }
}

// Stage 1: coalesced slab reduction of partials [NBLK][384] -> out2 [RBLK][384]
__global__ __launch_bounds__(384) void bn_reduce1(const float* __restrict__ partials,
                                                  float* __restrict__ out2) {
  const int b = blockIdx.x, t = threadIdx.x;
  const float* p = partials + (size_t)b * SLAB * 384;
  float v = 0.f;
#pragma unroll
  for (int r = 0; r < SLAB; ++r) v += p[r * 384 + t];
  out2[b * 384 + t] = v;
}

// Stage 2: final reduce + BN affine params; also zeroes the loss accumulator.
__global__ __launch_bounds__(384) void bn_fin2(
    const float* __restrict__ out2, const float* __restrict__ g,
    const float* __restrict__ be, float* __restrict__ scale,
    float* __restrict__ shift, float* accum) {
  __shared__ float tot[384];
  const int t = threadIdx.x;
  float v = 0.f;
  for (int b = 0; b < RBLK; ++b) v += out2[b * 384 + t];
  tot[t] = v;
  __syncthreads();
  if (t < 192) {
    float s = tot[t], q = tot[t + 192];
    float mean = s / (float)NROWS;
    float var = q / (float)NROWS - mean * mean;
    float inv = rsqrtf(var + BN_EPS);
    float sc = g[t] * inv;
    scale[t] = sc;
    shift[t] = be[t] - mean * sc;
  }
  if (t == 0) *accum = 0.f;
}

// BN2+ReLU + MFMA Linear[192x16pad] + sigmoid + log_softmax + NLL accumulate.
__global__ __launch_bounds__(256) void final_loss(
    const u16* __restrict__ Y2, const int* __restrict__ labels,
    const float* __restrict__ scale2, const float* __restrict__ shift2,
    const u16* __restrict__ W3t, const float* __restrict__ b3, float* accum) {
  __shared__ u16 Hs[RPB][200];  // 400B pitch: 8B-aligned rows, fits 3 blocks/CU
  __shared__ float red[4];
  const int t = threadIdx.x;
  const size_t row0 = (size_t)blockIdx.x * RPB;

#pragma unroll
  for (int j = 0; j < 12; ++j) {
    int e = j * 256 + t;
    int r = e / 24, cb8 = (e % 24) * 8;
    uint4 p = *(const uint4*)(Y2 + (row0 + r) * DIM + cb8);
    float4 sc0 = *(const float4*)&scale2[cb8];
    float4 sc1 = *(const float4*)&scale2[cb8 + 4];
    float4 sh0 = *(const float4*)&shift2[cb8];
    float4 sh1 = *(const float4*)&shift2[cb8 + 4];
    u32 pw[4] = {p.x, p.y, p.z, p.w};
    float scv[8] = {sc0.x, sc0.y, sc0.z, sc0.w, sc1.x, sc1.y, sc1.z, sc1.w};
    float shv[8] = {sh0.x, sh0.y, sh0.z, sh0.w, sh1.x, sh1.y, sh1.z, sh1.w};
    u16 o[8];
#pragma unroll
    for (int i = 0; i < 4; ++i) {
      float lo = b2f((u16)(pw[i] & 0xffffu));
      float hi = b2f((u16)(pw[i] >> 16));
      o[2 * i]     = f2b(fmaxf(lo * scv[2 * i] + shv[2 * i], 0.f));
      o[2 * i + 1] = f2b(fmaxf(hi * scv[2 * i + 1] + shv[2 * i + 1], 0.f));
    }
    ushort4 o0 = {o[0], o[1], o[2], o[3]};
    ushort4 o1 = {o[4], o[5], o[6], o[7]};
    *(ushort4*)&Hs[r][cb8] = o0;
    *(ushort4*)&Hs[r][cb8 + 4] = o1;
  }
  __syncthreads();

  const int lane = t & 63, wv = t >> 6;
  const int lr = lane & 15, g = lane >> 4, kg = g * 8;
  bf16x8 b[6];
#pragma unroll
  for (int ks = 0; ks < 6; ++ks)
    b[ks] = *(const bf16x8*)(W3t + lr * DIM + ks * 32 + kg);
  const float b3v = (lr < 8) ? b3[lr] : 0.f;

  float contrib = 0.f;
#pragma unroll
  for (int tl = 0; tl < 2; ++tl) {
    const int rbase = wv * 32 + tl * 16;
    f32x4 acc = (f32x4){0.f, 0.f, 0.f, 0.f};
#pragma unroll
    for (int ks = 0; ks < 6; ++ks) {
      const int k0 = ks * 32 + kg;
      union { bf16x8 v8; bf16x4 v4[2]; } ua;
      ua.v4[0] = *(const bf16x4*)&Hs[rbase + lr][k0];
      ua.v4[1] = *(const bf16x4*)&Hs[rbase + lr][k0 + 4];
      acc = __builtin_amdgcn_mfma_f32_16x16x32_bf16(ua.v8, b[ks], acc, 0, 0, 0);
    }
    // lane: rows rbase+g*4+i, class col = lr (0-7 valid, 8-15 pad)
#pragma unroll
    for (int i = 0; i < 4; ++i) {
      float p = 1.f / (1.f + __expf(-(acc[i] + b3v)));
      float m = p;
      m = fmaxf(m, __shfl_xor(m, 1));
      m = fmaxf(m, __shfl_xor(m, 2));
      m = fmaxf(m, __shfl_xor(m, 4));
      float e = __expf(p - m);
      e += __shfl_xor(e, 1);
      e += __shfl_xor(e, 2);
      e += __shfl_xor(e, 4);
      int lab = labels[row0 + rbase + g * 4 + i];
      if (lr == lab) contrib += m + __logf(e) - p;
    }
  }
#pragma unroll
  for (int off = 1; off < 64; off <<= 1) contrib += __shfl_xor(contrib, off);
  if (lane == 0) red[wv] = contrib;
  __syncthreads();
  if (t == 0) atomicAdd(accum, red[0] + red[1] + red[2] + red[3]);
}

__global__ void finalize(const float* __restrict__ accum, float* __restrict__ out) {
  if (threadIdx.x == 0) out[0] = accum[0] / (float)NROWS;
}

extern "C" void kernel_launch(void* const* d_in, const int* in_sizes, int n_in,
                              void* d_out, int out_size, void* d_ws, size_t ws_size,
                              hipStream_t stream) {
  const float* inputs = (const float*)d_in[0];
  const int* labels   = (const int*)d_in[1];
  const float* W1  = (const float*)d_in[2];
  const float* b1  = (const float*)d_in[3];
  const float* g1  = (const float*)d_in[4];
  const float* be1 = (const float*)d_in[5];
  const float* W2  = (const float*)d_in[6];
  const float* b2  = (const float*)d_in[7];
  const float* g2  = (const float*)d_in[8];
  const float* be2 = (const float*)d_in[9];
  const float* W3  = (const float*)d_in[10];
  const float* b3  = (const float*)d_in[11];
  float* out = (float*)d_out;

  char* ws = (char*)d_ws;
  u16* W1t      = (u16*)(ws + 0);        // 73728
  u16* W2t      = (u16*)(ws + 73728);    // 73728
  u16* W3t      = (u16*)(ws + 147456);   // 6144
  float* scale1 = (float*)(ws + 153600);
  float* shift1 = (float*)(ws + 154368);
  float* scale2 = (float*)(ws + 155136);
  float* shift2 = (float*)(ws + 155904);
  float* accum  = (float*)(ws + 156672);
  float* out2   = (float*)(ws + 157184);   // 125*384*4 = 192000
  float* partials = (float*)(ws + 360448); // 3125*384*4 = 4.8 MB
  u16* Ybuf     = (u16*)(ws + 8000000);    // 400000*192*2 = 153.6 MB

  prep_w<<<300, 256, 0, stream>>>(W1, W2, W3, W1t, W2t, W3t);
  gemm_bn<1><<<NBLK, 256, 0, stream>>>(inputs, Ybuf, W1t, b1, nullptr, nullptr, partials);
  bn_reduce1<<<RBLK, 384, 0, stream>>>(partials, out2);
  bn_fin2<<<1, 384, 0, stream>>>(out2, g1, be1, scale1, shift1, accum);
  gemm_bn<2><<<NBLK, 256, 0, stream>>>(nullptr, Ybuf, W2t, b2, scale1, shift1, partials);
  bn_reduce1<<<RBLK, 384, 0, stream>>>(partials, out2);
  bn_fin2<<<1, 384, 0, stream>>>(out2, g2, be2, scale2, shift2, accum);
  final_loss<<<NBLK, 256, 0, stream>>>(Ybuf, labels, scale2, shift2, W3t, b3, accum);
  finalize<<<1, 64, 0, stream>>>(accum, out);
}

// Round 3
// 289.558 us; speedup vs baseline: 1.2012x; 1.1116x over previous
//
#include <hip/hip_runtime.h>

typedef unsigned short u16;
typedef unsigned int u32;
typedef __attribute__((ext_vector_type(8))) short bf16x8;
typedef __attribute__((ext_vector_type(2))) float f32x2;
typedef __attribute__((ext_vector_type(4))) float f32x4;

#define NROWS 400000
#define DIM 192
#define RPB 128
#define NBLK (NROWS / RPB) /* 3125 */
#define PSTRIDE 3136       /* padded NBLK for col-major partials */
#define LDW 208            /* LDS pitch in u16 (416B rows, 16B aligned) */
#define BN_EPS 1e-5f

__device__ __forceinline__ u16 f2b(float f) {
  union { float f; u32 u; } v; v.f = f;
  return (u16)((v.u + 0x7fffu + ((v.u >> 16) & 1u)) >> 16);
}
__device__ __forceinline__ float b2f(u16 h) {
  union { u32 u; float f; } v; v.u = ((u32)h) << 16;
  return v.f;
}

#if __has_builtin(__builtin_amdgcn_cvt_pk_fp8_f32) && __has_builtin(__builtin_amdgcn_cvt_pk_f32_fp8)
#define HW_FP8 1
#endif

#ifndef HW_FP8
__device__ __forceinline__ u32 enc1_fp8(float f) {  // f32 -> e4m3fn, RNE
  float a = fabsf(f);
  u32 sg = (__float_as_uint(f) >> 24) & 0x80u;
  a = fminf(a, 448.f);
  u32 em;
  if (a >= 0.015625f) {
    u32 b = __float_as_uint(a);
    b += 0x0007FFFFu + ((b >> 20) & 1u);
    em = ((b >> 20) & 0xFFFu) - 960u;
  } else {
    em = (u32)(int)rintf(a * 512.f);
  }
  return sg | em;
}
__device__ __forceinline__ float dec1_fp8(u32 b) {
  u32 em = b & 0x7Fu;
  float vn = __uint_as_float((em + 960u) << 20);
  float vd = (float)em * 0.001953125f;
  float v = (em >= 8u) ? vn : vd;
  return (b & 0x80u) ? -v : v;
}
#endif

__device__ __forceinline__ u32 pack4_fp8(float f0, float f1, float f2, float f3) {
#ifdef HW_FP8
  int w = 0;
  w = __builtin_amdgcn_cvt_pk_fp8_f32(f0, f1, w, false);
  w = __builtin_amdgcn_cvt_pk_fp8_f32(f2, f3, w, true);
  return (u32)w;
#else
  return enc1_fp8(f0) | (enc1_fp8(f1) << 8) | (enc1_fp8(f2) << 16) | (enc1_fp8(f3) << 24);
#endif
}

__device__ __forceinline__ void unpack8_fp8(uint2 p, float (&f)[8]) {
#ifdef HW_FP8
  f32x2 v0 = __builtin_amdgcn_cvt_pk_f32_fp8(p.x, false);
  f32x2 v1 = __builtin_amdgcn_cvt_pk_f32_fp8(p.x, true);
  f32x2 v2 = __builtin_amdgcn_cvt_pk_f32_fp8(p.y, false);
  f32x2 v3 = __builtin_amdgcn_cvt_pk_f32_fp8(p.y, true);
  f[0] = v0[0]; f[1] = v0[1]; f[2] = v1[0]; f[3] = v1[1];
  f[4] = v2[0]; f[5] = v2[1]; f[6] = v3[0]; f[7] = v3[1];
#else
#pragma unroll
  for (int i = 0; i < 4; ++i) f[i] = dec1_fp8((p.x >> (8 * i)) & 0xFFu);
#pragma unroll
  for (int i = 0; i < 4; ++i) f[4 + i] = dec1_fp8((p.y >> (8 * i)) & 0xFFu);
#endif
}

// Weights -> bf16, transposed col-major. W3 padded to 16 cols (8 zeros).
__global__ void prep_w(const float* __restrict__ W1, const float* __restrict__ W2,
                       const float* __restrict__ W3, u16* __restrict__ W1t,
                       u16* __restrict__ W2t, u16* __restrict__ W3t) {
  int idx = blockIdx.x * 256 + threadIdx.x;
  if (idx < DIM * DIM) {
    int h = idx / DIM, d = idx % DIM;
    W1t[idx] = f2b(W1[d * DIM + h]);
    W2t[idx] = f2b(W2[d * DIM + h]);
  } else if (idx < DIM * DIM + 16 * DIM) {
    int j = idx - DIM * DIM;
    int c = j / DIM, k = j % DIM;
    W3t[j] = (c < 8) ? f2b(W3[k * 8 + c]) : (u16)0;
  }
}

// Fused GEMM (+bias) + per-block column (sum,sumsq) partials (col-major out).
// LAYER==1: A = X (fp32->bf16). LAYER==2: A = ReLU(BN1(fp8 Y1)), in-place fp8 out.
template <int LAYER>
__global__ __launch_bounds__(256, 3) void gemm_bn(
    const float* __restrict__ Xf, const u32* __restrict__ Yin_,
    u32* __restrict__ Yout, const u16* __restrict__ Wt,
    const float* __restrict__ bias, const float* __restrict__ scale_in,
    const float* __restrict__ shift_in, float* __restrict__ pT) {
  __shared__ u16 As[RPB][LDW];
  const int t = threadIdx.x;
  const int bid = blockIdx.x;
  const size_t row0 = (size_t)bid * RPB;

  if (LAYER == 1) {
    const float4* Xv = (const float4*)(Xf + row0 * DIM);
#pragma unroll
    for (int j = 0; j < 24; ++j) {
      int e = j * 256 + t;  // 128 rows x 48 float4
      int r = e / 48, c4 = e % 48;
      float4 v = Xv[e];
      ushort4 o = {f2b(v.x), f2b(v.y), f2b(v.z), f2b(v.w)};
      *(ushort4*)&As[r][c4 * 4] = o;
    }
  } else {
    const uint2* Yin2 = (const uint2*)(Yin_ + row0 * 48);
#pragma unroll
    for (int j = 0; j < 12; ++j) {
      int e = j * 256 + t;  // 128 rows x 24 uint2 (8 fp8 each)
      int r = e / 24, c8 = e % 24;
      int cb8 = c8 * 8;
      uint2 p = Yin2[r * 24 + c8];
      float f[8];
      unpack8_fp8(p, f);
      float4 sc0 = *(const float4*)&scale_in[cb8];
      float4 sc1 = *(const float4*)&scale_in[cb8 + 4];
      float4 sh0 = *(const float4*)&shift_in[cb8];
      float4 sh1 = *(const float4*)&shift_in[cb8 + 4];
      float scv[8] = {sc0.x, sc0.y, sc0.z, sc0.w, sc1.x, sc1.y, sc1.z, sc1.w};
      float shv[8] = {sh0.x, sh0.y, sh0.z, sh0.w, sh1.x, sh1.y, sh1.z, sh1.w};
      u32 w[4];
#pragma unroll
      for (int i = 0; i < 4; ++i) {
        float h0 = fmaxf(f[2 * i] * scv[2 * i] + shv[2 * i], 0.f);
        float h1 = fmaxf(f[2 * i + 1] * scv[2 * i + 1] + shv[2 * i + 1], 0.f);
        w[i] = (u32)f2b(h0) | ((u32)f2b(h1) << 16);
      }
      uint4 wq = {w[0], w[1], w[2], w[3]};
      *(uint4*)&As[r][cb8] = wq;
    }
  }
  __syncthreads();

  const int lane = t & 63, wv = t >> 6;
  const int cb = wv * 48;  // wave owns 48 output cols
  const int lr = lane & 15;
  const int g = lane >> 4;  // 0..3
  const int kg = g * 8;

  f32x4 acc[8][3];
#pragma unroll
  for (int rt = 0; rt < 8; ++rt)
#pragma unroll
    for (int ct = 0; ct < 3; ++ct) acc[rt][ct] = (f32x4){0.f, 0.f, 0.f, 0.f};

#pragma unroll
  for (int ks = 0; ks < 6; ++ks) {
    const int k0 = ks * 32 + kg;
    bf16x8 b0 = *(const bf16x8*)(Wt + (size_t)(cb + lr) * DIM + k0);
    bf16x8 b1 = *(const bf16x8*)(Wt + (size_t)(cb + 16 + lr) * DIM + k0);
    bf16x8 b2 = *(const bf16x8*)(Wt + (size_t)(cb + 32 + lr) * DIM + k0);
#pragma unroll
    for (int rt = 0; rt < 8; ++rt) {
      bf16x8 a = *(const bf16x8*)&As[rt * 16 + lr][k0];
      acc[rt][0] = __builtin_amdgcn_mfma_f32_16x16x32_bf16(b0, a, acc[rt][0], 0, 0, 0);
      acc[rt][1] = __builtin_amdgcn_mfma_f32_16x16x32_bf16(b1, a, acc[rt][1], 0, 0, 0);
      acc[rt][2] = __builtin_amdgcn_mfma_f32_16x16x32_bf16(b2, a, acc[rt][2], 0, 0, 0);
    }
  }

  // Epilogue: lane holds row rt*16+lr, cols cb+ct*16+g*4+{0..3} -> fp8 u32 store
  float4 bl[3];
#pragma unroll
  for (int ct = 0; ct < 3; ++ct) bl[ct] = *(const float4*)&bias[cb + ct * 16 + g * 4];
  f32x4 s[3], q[3];
#pragma unroll
  for (int ct = 0; ct < 3; ++ct) { s[ct] = (f32x4){0,0,0,0}; q[ct] = (f32x4){0,0,0,0}; }
  u32* Yo = Yout + row0 * 48;
#pragma unroll
  for (int rt = 0; rt < 8; ++rt) {
    const int row = rt * 16 + lr;
#pragma unroll
    for (int ct = 0; ct < 3; ++ct) {
      f32x4 v = acc[rt][ct];
      float f0 = v[0] + bl[ct].x, f1 = v[1] + bl[ct].y;
      float f2 = v[2] + bl[ct].z, f3 = v[3] + bl[ct].w;
      Yo[(size_t)row * 48 + wv * 12 + ct * 4 + g] = pack4_fp8(f0, f1, f2, f3);
      s[ct][0] += f0; s[ct][1] += f1; s[ct][2] += f2; s[ct][3] += f3;
      q[ct][0] += f0 * f0; q[ct][1] += f1 * f1; q[ct][2] += f2 * f2; q[ct][3] += f3 * f3;
    }
  }
  // reduce over rows (lane&15 dimension)
#pragma unroll
  for (int ct = 0; ct < 3; ++ct)
#pragma unroll
    for (int off = 1; off <= 8; off <<= 1)
#pragma unroll
      for (int i = 0; i < 4; ++i) {
        s[ct][i] += __shfl_xor(s[ct][i], off);
        q[ct][i] += __shfl_xor(q[ct][i], off);
      }
  if (lr == 0) {
#pragma unroll
    for (int ct = 0; ct < 3; ++ct)
#pragma unroll
      for (int i = 0; i < 4; ++i) {
        int c = cb + ct * 16 + g * 4 + i;
        pT[(size_t)c * PSTRIDE + bid] = s[ct][i];
        pT[(size_t)(c + DIM) * PSTRIDE + bid] = q[ct][i];
      }
  }
}

// One block per column: coalesced reduce of col-major partials -> BN affine.
__global__ __launch_bounds__(256) void bn_fin(
    const float* __restrict__ pT, const float* __restrict__ gam,
    const float* __restrict__ be, float* __restrict__ scale,
    float* __restrict__ shift, float* accum) {
  const int c = blockIdx.x, t = threadIdx.x;
  const float* ps = pT + (size_t)c * PSTRIDE;
  const float* pq = pT + (size_t)(c + DIM) * PSTRIDE;
  float s = 0.f, q = 0.f;
  for (int i = t; i < NBLK; i += 256) { s += ps[i]; q += pq[i]; }
#pragma unroll
  for (int off = 1; off < 64; off <<= 1) { s += __shfl_xor(s, off); q += __shfl_xor(q, off); }
  __shared__ float ss[4], qq[4];
  int lane = t & 63, w = t >> 6;
  if (lane == 0) { ss[w] = s; qq[w] = q; }
  __syncthreads();
  if (t == 0) {
    s = ss[0] + ss[1] + ss[2] + ss[3];
    q = qq[0] + qq[1] + qq[2] + qq[3];
    float mean = s / (float)NROWS;
    float var = q / (float)NROWS - mean * mean;
    float inv = rsqrtf(var + BN_EPS);
    float sc = gam[c] * inv;
    scale[c] = sc;
    shift[c] = be[c] - mean * sc;
    if (c == 0) *accum = 0.f;
  }
}

// BN2+ReLU + MFMA Linear[192x16pad] + sigmoid + log_softmax + NLL.
// No LDS staging: zero reuse -> direct per-lane fragment loads from global.
__global__ __launch_bounds__(256, 4) void final_loss(
    const u32* __restrict__ Y2, const int* __restrict__ labels,
    const float* __restrict__ scale2, const float* __restrict__ shift2,
    const u16* __restrict__ W3t, const float* __restrict__ b3, float* accum) {
  __shared__ float red[4];
  const int t = threadIdx.x;
  const size_t row0 = (size_t)blockIdx.x * RPB;
  const int lane = t & 63, wv = t >> 6;
  const int lr = lane & 15, g = lane >> 4, kg = g * 8;

  bf16x8 b[6];
#pragma unroll
  for (int ks = 0; ks < 6; ++ks)
    b[ks] = *(const bf16x8*)(W3t + lr * DIM + ks * 32 + kg);
  const float b3v = (lr < 8) ? b3[lr] : 0.f;

  float contrib = 0.f;
#pragma unroll
  for (int tl = 0; tl < 2; ++tl) {
    const int rbase = wv * 32 + tl * 16;
    const uint2* Yrow2 = (const uint2*)(Y2 + (row0 + rbase + lr) * 48);
    f32x4 acc = (f32x4){0.f, 0.f, 0.f, 0.f};
#pragma unroll
    for (int ks = 0; ks < 6; ++ks) {
      const int k0 = ks * 32 + kg;
      uint2 p = Yrow2[ks * 4 + g];
      float f[8];
      unpack8_fp8(p, f);
      float4 sc0 = *(const float4*)&scale2[k0];
      float4 sc1 = *(const float4*)&scale2[k0 + 4];
      float4 sh0 = *(const float4*)&shift2[k0];
      float4 sh1 = *(const float4*)&shift2[k0 + 4];
      float scv[8] = {sc0.x, sc0.y, sc0.z, sc0.w, sc1.x, sc1.y, sc1.z, sc1.w};
      float shv[8] = {sh0.x, sh0.y, sh0.z, sh0.w, sh1.x, sh1.y, sh1.z, sh1.w};
      u32 w[4];
#pragma unroll
      for (int i = 0; i < 4; ++i) {
        float h0 = fmaxf(f[2 * i] * scv[2 * i] + shv[2 * i], 0.f);
        float h1 = fmaxf(f[2 * i + 1] * scv[2 * i + 1] + shv[2 * i + 1], 0.f);
        w[i] = (u32)f2b(h0) | ((u32)f2b(h1) << 16);
      }
      union { uint4 u4; bf16x8 v; } ua;
      ua.u4 = (uint4){w[0], w[1], w[2], w[3]};
      acc = __builtin_amdgcn_mfma_f32_16x16x32_bf16(ua.v, b[ks], acc, 0, 0, 0);
    }
    // lane: rows rbase+g*4+i, class col = lr (0-7 valid, 8-15 pad)
#pragma unroll
    for (int i = 0; i < 4; ++i) {
      float p = 1.f / (1.f + __expf(-(acc[i] + b3v)));
      float m = p;
      m = fmaxf(m, __shfl_xor(m, 1));
      m = fmaxf(m, __shfl_xor(m, 2));
      m = fmaxf(m, __shfl_xor(m, 4));
      float e = __expf(p - m);
      e += __shfl_xor(e, 1);
      e += __shfl_xor(e, 2);
      e += __shfl_xor(e, 4);
      int lab = labels[row0 + rbase + g * 4 + i];
      if (lr == lab) contrib += m + __logf(e) - p;
    }
  }
#pragma unroll
  for (int off = 1; off < 64; off <<= 1) contrib += __shfl_xor(contrib, off);
  if (lane == 0) red[wv] = contrib;
  __syncthreads();
  if (t == 0) atomicAdd(accum, red[0] + red[1] + red[2] + red[3]);
}

__global__ void finalize(const float* __restrict__ accum, float* __restrict__ out) {
  if (threadIdx.x == 0) out[0] = accum[0] / (float)NROWS;
}

extern "C" void kernel_launch(void* const* d_in, const int* in_sizes, int n_in,
                              void* d_out, int out_size, void* d_ws, size_t ws_size,
                              hipStream_t stream) {
  const float* inputs = (const float*)d_in[0];
  const int* labels   = (const int*)d_in[1];
  const float* W1  = (const float*)d_in[2];
  const float* b1  = (const float*)d_in[3];
  const float* g1  = (const float*)d_in[4];
  const float* be1 = (const float*)d_in[5];
  const float* W2  = (const float*)d_in[6];
  const float* b2  = (const float*)d_in[7];
  const float* g2  = (const float*)d_in[8];
  const float* be2 = (const float*)d_in[9];
  const float* W3  = (const float*)d_in[10];
  const float* b3  = (const float*)d_in[11];
  float* out = (float*)d_out;

  char* ws = (char*)d_ws;
  u16* W1t      = (u16*)(ws + 0);        // 73728
  u16* W2t      = (u16*)(ws + 73728);    // 73728
  u16* W3t      = (u16*)(ws + 147456);   // 6144
  float* scale1 = (float*)(ws + 153600);
  float* shift1 = (float*)(ws + 154368);
  float* scale2 = (float*)(ws + 155136);
  float* shift2 = (float*)(ws + 155904);
  float* accum  = (float*)(ws + 156672);
  float* pT     = (float*)(ws + 160000);   // 384*3136*4 = 4.82 MB (col-major)
  u32* Ybuf     = (u32*)(ws + 8000000);    // 400000*48*4 = 76.8 MB (fp8 packed)

  prep_w<<<156, 256, 0, stream>>>(W1, W2, W3, W1t, W2t, W3t);
  gemm_bn<1><<<NBLK, 256, 0, stream>>>(inputs, nullptr, Ybuf, W1t, b1, nullptr, nullptr, pT);
  bn_fin<<<DIM, 256, 0, stream>>>(pT, g1, be1, scale1, shift1, accum);
  gemm_bn<2><<<NBLK, 256, 0, stream>>>(nullptr, Ybuf, Ybuf, W2t, b2, scale1, shift1, pT);
  bn_fin<<<DIM, 256, 0, stream>>>(pT, g2, be2, scale2, shift2, accum);
  final_loss<<<NBLK, 256, 0, stream>>>(Ybuf, labels, scale2, shift2, W3t, b3, accum);
  finalize<<<1, 64, 0, stream>>>(accum, out);
}